// Round 1
// baseline (1747.938 us; speedup 1.0000x reference)
//
#include <hip/hip_runtime.h>
#include <hip/hip_bf16.h>
#include <stdint.h>

// B=8192, D_IN=1024, D_HID=4096, D_OUT=1024, E=8
#define BB 8192
#define DIN 1024
#define DHID 4096
#define DOUT 1024
#define NEXP 8
#define GH_N 2048  // D_HID/2

typedef __attribute__((ext_vector_type(8))) __bf16 bf16x8;
typedef __attribute__((ext_vector_type(4))) float f32x4;

__device__ inline unsigned short f2bf(float f) {
  unsigned u = __builtin_bit_cast(unsigned, f);
  u = (u + 0x7FFFu + ((u >> 16) & 1u)) >> 16;
  return (unsigned short)u;
}
__device__ inline float b2f(unsigned short s) {
  return __builtin_bit_cast(float, (unsigned)s << 16);
}

// ---------------- elementwise f32 -> bf16 ----------------
__global__ void cvt_f32_bf16(const float* __restrict__ in,
                             unsigned short* __restrict__ out, int n4) {
  int i = blockIdx.x * blockDim.x + threadIdx.x;
  if (i >= n4) return;
  float4 v = ((const float4*)in)[i];
  ushort4 o;
  o.x = f2bf(v.x); o.y = f2bf(v.y); o.z = f2bf(v.z); o.w = f2bf(v.w);
  ((ushort4*)out)[i] = o;
}

// ---------------- transpose + convert: in[R][C] f32 -> out[C][R] bf16 ----------------
__global__ void transpose_cvt(const float* __restrict__ in,
                              unsigned short* __restrict__ out, int R, int C) {
  __shared__ float tile[32][33];
  int c0 = blockIdx.x * 32, r0 = blockIdx.y * 32;
  int tx = threadIdx.x & 31, ty = threadIdx.x >> 5;  // ty in 0..7
#pragma unroll
  for (int i = 0; i < 4; ++i)
    tile[ty + i * 8][tx] = in[(size_t)(r0 + ty + i * 8) * C + c0 + tx];
  __syncthreads();
#pragma unroll
  for (int i = 0; i < 4; ++i)
    out[(size_t)(c0 + ty + i * 8) * R + r0 + tx] = f2bf(tile[tx][ty + i * 8]);
}

// ---------------- async global->LDS 16B ----------------
__device__ inline void gload16(const void* g, void* l) {
  __builtin_amdgcn_global_load_lds(
      (const __attribute__((address_space(1))) void*)g,
      (__attribute__((address_space(3))) void*)l, 16, 0, 0);
}

// ---------------- GEMM: C[M,N] = A[M,K] * Bt[N,K]^T, bf16 in, fp32 acc ----------------
// EPI 0: outb = bf16(relu(acc + bias[col]))
// EPI 1: outf = (accum? outf : 0) + gates[row*8+eidx] * (acc + bias[col])
template <int EPI>
__global__ void gemm_bt(const unsigned short* __restrict__ A,
                        const unsigned short* __restrict__ Bt,
                        int M, int N, int K,
                        const float* __restrict__ bias,
                        unsigned short* __restrict__ outb,
                        float* __restrict__ outf,
                        const float* __restrict__ gates,
                        int eidx, int accum) {
  __shared__ unsigned short As[128 * 32];
  __shared__ unsigned short Bs[128 * 32];
  const int t = threadIdx.x;
  const int lane = t & 63;
  const int wid = t >> 6;
  const int wm = wid >> 1, wn = wid & 1;
  const int m0 = blockIdx.y * 128, n0 = blockIdx.x * 128;

  // staging chunks: 512 16B-chunks per tile; physical chunk q: row=q>>2, cp=q&3,
  // logical k-chunk c = cp ^ ((row>>1)&3)   (XOR swizzle, same involution on read)
  const int q0 = wid * 64 + lane;
  const int q1 = 256 + wid * 64 + lane;
  const int rA0 = q0 >> 2, cA0 = (q0 & 3) ^ ((rA0 >> 1) & 3);
  const int rA1 = q1 >> 2, cA1 = (q1 & 3) ^ ((rA1 >> 1) & 3);

  auto stage = [&](int k0) {
    gload16(A + (size_t)(m0 + rA0) * K + k0 + cA0 * 8, (void*)(As + q0 * 8));
    gload16(A + (size_t)(m0 + rA1) * K + k0 + cA1 * 8, (void*)(As + q1 * 8));
    gload16(Bt + (size_t)(n0 + rA0) * K + k0 + cA0 * 8, (void*)(Bs + q0 * 8));
    gload16(Bt + (size_t)(n0 + rA1) * K + k0 + cA1 * 8, (void*)(Bs + q1 * 8));
  };

  const int l15 = lane & 15, lg = lane >> 4;
  int aoff[4], boff[4];
#pragma unroll
  for (int mi = 0; mi < 4; ++mi) {
    int r = wm * 64 + mi * 16 + l15;
    aoff[mi] = r * 32 + ((lg ^ ((r >> 1) & 3)) << 3);
  }
#pragma unroll
  for (int ni = 0; ni < 4; ++ni) {
    int r = wn * 64 + ni * 16 + l15;
    boff[ni] = r * 32 + ((lg ^ ((r >> 1) & 3)) << 3);
  }

  f32x4 acc[4][4];
  const f32x4 zero = {0.f, 0.f, 0.f, 0.f};
#pragma unroll
  for (int mi = 0; mi < 4; ++mi)
#pragma unroll
    for (int ni = 0; ni < 4; ++ni) acc[mi][ni] = zero;

  stage(0);
  const int nkt = K >> 5;
  for (int kt = 0; kt < nkt; ++kt) {
    __syncthreads();  // staging (vmcnt) drained here
    bf16x8 af[4], bfr[4];
#pragma unroll
    for (int mi = 0; mi < 4; ++mi) af[mi] = *(const bf16x8*)(As + aoff[mi]);
#pragma unroll
    for (int ni = 0; ni < 4; ++ni) bfr[ni] = *(const bf16x8*)(Bs + boff[ni]);
#pragma unroll
    for (int mi = 0; mi < 4; ++mi)
#pragma unroll
      for (int ni = 0; ni < 4; ++ni)
        acc[mi][ni] = __builtin_amdgcn_mfma_f32_16x16x32_bf16(
            af[mi], bfr[ni], acc[mi][ni], 0, 0, 0);
    __syncthreads();  // all reads done before overwrite
    if (kt + 1 < nkt) stage((kt + 1) << 5);
  }

  // epilogue: D row = lg*4 + reg (within 16), col = l15 (m89-verified)
  const int rb = m0 + wm * 64 + (lg << 2);
  const int cb = n0 + wn * 64 + l15;
  if (EPI == 0) {
#pragma unroll
    for (int mi = 0; mi < 4; ++mi) {
#pragma unroll
      for (int ni = 0; ni < 4; ++ni) {
        int col = cb + ni * 16;
        float bv = bias[col];
#pragma unroll
        for (int r = 0; r < 4; ++r) {
          int row = rb + mi * 16 + r;
          float v = acc[mi][ni][r] + bv;
          outb[(size_t)row * N + col] = f2bf(fmaxf(v, 0.f));
        }
      }
    }
  } else {
#pragma unroll
    for (int mi = 0; mi < 4; ++mi) {
      float g[4];
#pragma unroll
      for (int r = 0; r < 4; ++r)
        g[r] = gates[(size_t)(rb + mi * 16 + r) * NEXP + eidx];
#pragma unroll
      for (int ni = 0; ni < 4; ++ni) {
        int col = cb + ni * 16;
        float bv = bias[col];
#pragma unroll
        for (int r = 0; r < 4; ++r) {
          size_t o = (size_t)(rb + mi * 16 + r) * N + col;
          float v = (acc[mi][ni][r] + bv) * g[r];
          outf[o] = accum ? outf[o] + v : v;
        }
      }
    }
  }
}

// ---------------- gating head: logits = gh(bf16) @ gW2 + gb2, softmax over 8 ----------------
__global__ void gating_head(const unsigned short* __restrict__ gh,
                            const float* __restrict__ gW2,
                            const float* __restrict__ gb2,
                            float* __restrict__ gws,
                            float* __restrict__ g1,
                            float* __restrict__ g2, int B, int Kh) {
  int gw = (blockIdx.x * blockDim.x + threadIdx.x) >> 6;
  int lane = threadIdx.x & 63;
  int nw = (gridDim.x * blockDim.x) >> 6;
  for (int row = gw; row < B; row += nw) {
    float s[8] = {0, 0, 0, 0, 0, 0, 0, 0};
    for (int k = lane; k < Kh; k += 64) {
      float hv = b2f(gh[(size_t)row * Kh + k]);
      const float* w = gW2 + (size_t)k * 8;
#pragma unroll
      for (int e = 0; e < 8; ++e) s[e] += hv * w[e];
    }
#pragma unroll
    for (int e = 0; e < 8; ++e) {
#pragma unroll
      for (int off = 32; off > 0; off >>= 1) s[e] += __shfl_xor(s[e], off, 64);
    }
    if (lane == 0) {
      float l[8], m = -1e30f;
#pragma unroll
      for (int e = 0; e < 8; ++e) {
        l[e] = s[e] + gb2[e];
        m = fmaxf(m, l[e]);
      }
      float sum = 0.f;
#pragma unroll
      for (int e = 0; e < 8; ++e) {
        l[e] = expf(l[e] - m);
        sum += l[e];
      }
      float inv = 1.f / sum;
#pragma unroll
      for (int e = 0; e < 8; ++e) {
        float gv = l[e] * inv;
        gws[(size_t)row * 8 + e] = gv;
        g1[(size_t)row * 8 + e] = gv;
        g2[(size_t)row * 8 + e] = gv;
      }
    }
  }
}

extern "C" void kernel_launch(void* const* d_in, const int* in_sizes, int n_in,
                              void* d_out, int out_size, void* d_ws,
                              size_t ws_size, hipStream_t stream) {
  (void)in_sizes; (void)n_in; (void)out_size; (void)ws_size;
  const float* x   = (const float*)d_in[0];
  const float* gW1 = (const float*)d_in[1];
  const float* gb1 = (const float*)d_in[2];
  const float* gW2 = (const float*)d_in[3];
  const float* gb2 = (const float*)d_in[4];
  const float* eW1 = (const float*)d_in[5];
  const float* eb1 = (const float*)d_in[6];
  const float* eW2 = (const float*)d_in[7];
  const float* eb2 = (const float*)d_in[8];

  float* outC  = (float*)d_out;                       // [8192,1024]
  float* outG1 = outC + (size_t)BB * DOUT;            // [8192,8]
  float* outG2 = outG1 + (size_t)BB * NEXP;           // [8192,8]

  char* ws = (char*)d_ws;
  unsigned short* xb   = (unsigned short*)(ws);                 // 16,777,216 B
  unsigned short* gW1T = (unsigned short*)(ws + 16777216);      //  4,194,304 B
  unsigned short* gh   = (unsigned short*)(ws + 20971520);      // 33,554,432 B
  float*          gat  = (float*)(ws + 54525952);               //    262,144 B
  unsigned short* w1T  = (unsigned short*)(ws + 54788096);      //  8,388,608 B
  unsigned short* w2T  = (unsigned short*)(ws + 63176704);      //  8,388,608 B
  unsigned short* hbuf = (unsigned short*)(ws + 71565312);      // 67,108,864 B  (end 138,674,176)

  // x -> bf16
  cvt_f32_bf16<<<(BB * DIN / 4) / 256, 256, 0, stream>>>(x, xb, BB * DIN / 4);
  // gW1 [1024][2048] -> gW1T [2048][1024] bf16
  transpose_cvt<<<dim3(GH_N / 32, DIN / 32), 256, 0, stream>>>(gW1, gW1T, DIN, GH_N);
  // gh = relu(x @ gW1 + gb1)  [8192, 2048] bf16
  gemm_bt<0><<<dim3(GH_N / 128, BB / 128), 256, 0, stream>>>(
      xb, gW1T, BB, GH_N, DIN, gb1, gh, nullptr, nullptr, 0, 0);
  // gates = softmax(gh @ gW2 + gb2)
  gating_head<<<256, 256, 0, stream>>>(gh, gW2, gb2, gat, outG1, outG2, BB, GH_N);

  for (int e = 0; e < NEXP; ++e) {
    // eW1_e [1024][4096] -> w1T [4096][1024]
    transpose_cvt<<<dim3(DHID / 32, DIN / 32), 256, 0, stream>>>(
        eW1 + (size_t)e * DIN * DHID, w1T, DIN, DHID);
    // eW2_e [4096][1024] -> w2T [1024][4096]
    transpose_cvt<<<dim3(DOUT / 32, DHID / 32), 256, 0, stream>>>(
        eW2 + (size_t)e * DHID * DOUT, w2T, DHID, DOUT);
    // h = relu(x @ eW1_e + eb1_e)  [8192, 4096] bf16
    gemm_bt<0><<<dim3(DHID / 128, BB / 128), 256, 0, stream>>>(
        xb, w1T, BB, DHID, DIN, eb1 + (size_t)e * DHID, hbuf, nullptr, nullptr, 0, 0);
    // combined (+)= gates[:,e] * (h @ eW2_e + eb2_e)
    gemm_bt<1><<<dim3(DOUT / 128, BB / 128), 256, 0, stream>>>(
        hbuf, w2T, BB, DOUT, DHID, eb2 + (size_t)e * DOUT, nullptr, outC, gat, e, e > 0);
  }
}

// Round 2
// 1571.838 us; speedup vs baseline: 1.1120x; 1.1120x over previous
//
#include <hip/hip_runtime.h>
#include <hip/hip_bf16.h>
#include <stdint.h>

// B=8192, D_IN=1024, D_HID=4096, D_OUT=1024, E=8
#define BB 8192
#define DIN 1024
#define DHID 4096
#define DOUT 1024
#define NEXP 8
#define GH_N 2048  // D_HID/2

typedef __attribute__((ext_vector_type(8))) __bf16 bf16x8;
typedef __attribute__((ext_vector_type(4))) float f32x4;

__device__ inline unsigned short f2bf(float f) {
  unsigned u = __builtin_bit_cast(unsigned, f);
  u = (u + 0x7FFFu + ((u >> 16) & 1u)) >> 16;
  return (unsigned short)u;
}
__device__ inline float b2f(unsigned short s) {
  return __builtin_bit_cast(float, (unsigned)s << 16);
}

// ---------------- elementwise f32 -> bf16 ----------------
__global__ void cvt_f32_bf16(const float* __restrict__ in,
                             unsigned short* __restrict__ out, int n4) {
  int i = blockIdx.x * blockDim.x + threadIdx.x;
  if (i >= n4) return;
  float4 v = ((const float4*)in)[i];
  ushort4 o;
  o.x = f2bf(v.x); o.y = f2bf(v.y); o.z = f2bf(v.z); o.w = f2bf(v.w);
  ((ushort4*)out)[i] = o;
}

// ---------------- transpose + convert: in[R][C] f32 -> out[C][R] bf16 ----------------
__global__ void transpose_cvt(const float* __restrict__ in,
                              unsigned short* __restrict__ out, int R, int C) {
  __shared__ float tile[32][33];
  int c0 = blockIdx.x * 32, r0 = blockIdx.y * 32;
  int tx = threadIdx.x & 31, ty = threadIdx.x >> 5;  // ty in 0..7
#pragma unroll
  for (int i = 0; i < 4; ++i)
    tile[ty + i * 8][tx] = in[(size_t)(r0 + ty + i * 8) * C + c0 + tx];
  __syncthreads();
#pragma unroll
  for (int i = 0; i < 4; ++i)
    out[(size_t)(c0 + ty + i * 8) * R + r0 + tx] = f2bf(tile[tx][ty + i * 8]);
}

// ---------------- async global->LDS 16B ----------------
__device__ inline void gload16(const void* g, void* l) {
  __builtin_amdgcn_global_load_lds(
      (const __attribute__((address_space(1))) void*)g,
      (__attribute__((address_space(3))) void*)l, 16, 0, 0);
}

template <int N>
__device__ inline void waitv() {
  if constexpr (N == 0) asm volatile("s_waitcnt vmcnt(0)" ::: "memory");
  else if constexpr (N == 3) asm volatile("s_waitcnt vmcnt(3)" ::: "memory");
  else if constexpr (N == 4) asm volatile("s_waitcnt vmcnt(4)" ::: "memory");
  else asm volatile("s_waitcnt vmcnt(0)" ::: "memory");
}
__device__ inline void waitlgkm0() {
  asm volatile("s_waitcnt lgkmcnt(0)" ::: "memory");
  __builtin_amdgcn_sched_barrier(0);
}

// ---------------- pipelined GEMM: C[M,N] = A[M,K]*Bt[N,K]^T ----------------
// 8 waves (2M x 4N), BK=32, 4 LDS buffers, stage 2 tiles ahead, counted vmcnt.
// EPI 0: outb = bf16(relu(acc + bias[col]))
// EPI 1: outf = (accum? outf : 0) + gates[row*8+eidx]*(acc + bias[col])
template <int BM, int BN, int EPI>
__global__ __launch_bounds__(512, 2)
void gemm8(const unsigned short* __restrict__ A,
           const unsigned short* __restrict__ Bt,
           int M, int N, int K,
           const float* __restrict__ bias,
           unsigned short* __restrict__ outb,
           float* __restrict__ outf,
           const float* __restrict__ gates,
           int eidx, int accum) {
  constexpr int BK = 32;
  constexpr int RM = BM / 32;    // m-subtiles per wave
  constexpr int RN = BN / 64;    // n-subtiles per wave
  constexpr int P = (RM > 4) ? 2 : 1;  // phases per K-tile
  constexpr int MPP = RM / P;          // m-subtiles per phase
  constexpr int APT = BM / 128;        // A stage instrs/thread/tile
  constexpr int BPT = BN / 128;        // B stage instrs/thread/tile
  constexpr int S = APT + BPT;         // total stage instrs/thread/tile
  constexpr int ASZ = BM * BK;         // shorts per A buffer
  constexpr int BSZ = BN * BK;

  __shared__ unsigned short As[4 * ASZ];
  __shared__ unsigned short Bs[4 * BSZ];

  const int t = threadIdx.x;
  const int lane = t & 63;
  const int wid = t >> 6;   // 0..7
  const int wm = wid >> 2;  // 0..1
  const int wn = wid & 3;   // 0..3

  // bijective XCD swizzle (all grids are multiples of 8)
  const int nwg = gridDim.x;
  const int flat = blockIdx.x;
  const int swz = (flat & 7) * (nwg >> 3) + (flat >> 3);
  const int nbx = N / BN;
  const int bn = swz % nbx, bm = swz / nbx;
  const int m0 = bm * BM, n0 = bn * BN;

  // ---- staging: precompute per-thread source row/chunk (XOR swizzle) ----
  const unsigned short* aSrc[APT];
  const unsigned short* bSrc[BPT];
  int aQ[APT], bQ[BPT];
#pragma unroll
  for (int j = 0; j < APT; ++j) {
    int q = (wid * APT + j) * 64 + lane;
    int row = q >> 2, cp = q & 3;
    int c = cp ^ ((row >> 1) & 3);
    aSrc[j] = A + (size_t)(m0 + row) * K + c * 8;
    aQ[j] = q;
  }
#pragma unroll
  for (int j = 0; j < BPT; ++j) {
    int q = (wid * BPT + j) * 64 + lane;
    int row = q >> 2, cp = q & 3;
    int c = cp ^ ((row >> 1) & 3);
    bSrc[j] = Bt + (size_t)(n0 + row) * K + c * 8;
    bQ[j] = q;
  }
  auto stageA = [&](int T) {
    unsigned short* dst = As + (T & 3) * ASZ;
    const int k0 = T * BK;
#pragma unroll
    for (int j = 0; j < APT; ++j) gload16(aSrc[j] + k0, dst + aQ[j] * 8);
  };
  auto stageB = [&](int T) {
    unsigned short* dst = Bs + (T & 3) * BSZ;
    const int k0 = T * BK;
#pragma unroll
    for (int j = 0; j < BPT; ++j) gload16(bSrc[j] + k0, dst + bQ[j] * 8);
  };

  // ---- LDS read offsets (same XOR swizzle) ----
  const int l15 = lane & 15, lg = lane >> 4;
  int aoff[RM], boff[RN];
#pragma unroll
  for (int mi = 0; mi < RM; ++mi) {
    int r = wm * (BM / 2) + mi * 16 + l15;
    aoff[mi] = r * BK + ((lg ^ ((r >> 1) & 3)) << 3);
  }
#pragma unroll
  for (int ni = 0; ni < RN; ++ni) {
    int r = wn * (BN / 4) + ni * 16 + l15;
    boff[ni] = r * BK + ((lg ^ ((r >> 1) & 3)) << 3);
  }

  f32x4 acc[RM][RN];
  const f32x4 zero = {0.f, 0.f, 0.f, 0.f};
#pragma unroll
  for (int mi = 0; mi < RM; ++mi)
#pragma unroll
    for (int ni = 0; ni < RN; ++ni) acc[mi][ni] = zero;

  const int NT = K >> 5;

  // prologue: stage tiles 0 and 1; wait for tile 0
  stageA(0); stageB(0);
  stageA(1); stageB(1);
  waitv<S>();
  __builtin_amdgcn_s_barrier();

  for (int T = 0; T < NT; ++T) {
    const unsigned short* Ab = As + (T & 3) * ASZ;
    const unsigned short* Bb = Bs + (T & 3) * BSZ;
    bf16x8 bfr[RN], af[MPP];

    // ---- phase 0 ----
#pragma unroll
    for (int ni = 0; ni < RN; ++ni) bfr[ni] = *(const bf16x8*)(Bb + boff[ni]);
#pragma unroll
    for (int mi = 0; mi < MPP; ++mi) af[mi] = *(const bf16x8*)(Ab + aoff[mi]);
    if (T + 2 < NT) {
      stageA(T + 2);
      if (P == 1) stageB(T + 2);
    }
    __builtin_amdgcn_s_barrier();
    waitlgkm0();
    __builtin_amdgcn_s_setprio(1);
#pragma unroll
    for (int mi = 0; mi < MPP; ++mi)
#pragma unroll
      for (int ni = 0; ni < RN; ++ni)
        acc[mi][ni] = __builtin_amdgcn_mfma_f32_16x16x32_bf16(
            af[mi], bfr[ni], acc[mi][ni], 0, 0, 0);
    __builtin_amdgcn_s_setprio(0);
    if (P == 1) {
      if (T + 2 < NT) waitv<S>();
      else if (T + 2 == NT) waitv<0>();
    }
    __builtin_amdgcn_s_barrier();

    // ---- phase 1 (256-row tiles only) ----
    if (P == 2) {
#pragma unroll
      for (int mi = 0; mi < MPP; ++mi)
        af[mi] = *(const bf16x8*)(Ab + aoff[MPP + mi]);
      if (T + 2 < NT) stageB(T + 2);
      __builtin_amdgcn_s_barrier();
      waitlgkm0();
      __builtin_amdgcn_s_setprio(1);
#pragma unroll
      for (int mi = 0; mi < MPP; ++mi)
#pragma unroll
        for (int ni = 0; ni < RN; ++ni)
          acc[MPP + mi][ni] = __builtin_amdgcn_mfma_f32_16x16x32_bf16(
              af[mi], bfr[ni], acc[MPP + mi][ni], 0, 0, 0);
      __builtin_amdgcn_s_setprio(0);
      if (T + 2 < NT) waitv<S>();
      else if (T + 2 == NT) waitv<0>();
      __builtin_amdgcn_s_barrier();
    }
  }

  // ---- epilogue: D row = lg*4 + reg, col = l15 (m89-verified) ----
  const int rb = m0 + wm * (BM / 2) + (lg << 2);
  const int cb = n0 + wn * (BN / 4) + l15;
  if (EPI == 0) {
#pragma unroll
    for (int mi = 0; mi < RM; ++mi) {
#pragma unroll
      for (int ni = 0; ni < RN; ++ni) {
        int col = cb + ni * 16;
        float bv = bias[col];
#pragma unroll
        for (int r = 0; r < 4; ++r) {
          int row = rb + mi * 16 + r;
          float v = acc[mi][ni][r] + bv;
          outb[(size_t)row * N + col] = f2bf(fmaxf(v, 0.f));
        }
      }
    }
  } else {
#pragma unroll
    for (int mi = 0; mi < RM; ++mi) {
      float g[4];
#pragma unroll
      for (int r = 0; r < 4; ++r)
        g[r] = gates[(size_t)(rb + mi * 16 + r) * NEXP + eidx];
#pragma unroll
      for (int ni = 0; ni < RN; ++ni) {
        int col = cb + ni * 16;
        float bv = bias[col];
#pragma unroll
        for (int r = 0; r < 4; ++r) {
          size_t o = (size_t)(rb + mi * 16 + r) * N + col;
          float v = (acc[mi][ni][r] + bv) * g[r];
          outf[o] = accum ? outf[o] + v : v;
        }
      }
    }
  }
}

// ---------------- gating head: logits = gh(bf16) @ gW2 + gb2, softmax over 8 ----------------
__global__ void gating_head(const unsigned short* __restrict__ gh,
                            const float* __restrict__ gW2,
                            const float* __restrict__ gb2,
                            float* __restrict__ gws,
                            float* __restrict__ g1,
                            float* __restrict__ g2, int B, int Kh) {
  int gw = (blockIdx.x * blockDim.x + threadIdx.x) >> 6;
  int lane = threadIdx.x & 63;
  int nw = (gridDim.x * blockDim.x) >> 6;
  for (int row = gw; row < B; row += nw) {
    float s[8] = {0, 0, 0, 0, 0, 0, 0, 0};
    for (int k = lane; k < Kh; k += 64) {
      float hv = b2f(gh[(size_t)row * Kh + k]);
      const float* w = gW2 + (size_t)k * 8;
#pragma unroll
      for (int e = 0; e < 8; ++e) s[e] += hv * w[e];
    }
#pragma unroll
    for (int e = 0; e < 8; ++e) {
#pragma unroll
      for (int off = 32; off > 0; off >>= 1) s[e] += __shfl_xor(s[e], off, 64);
    }
    if (lane == 0) {
      float l[8], m = -1e30f;
#pragma unroll
      for (int e = 0; e < 8; ++e) {
        l[e] = s[e] + gb2[e];
        m = fmaxf(m, l[e]);
      }
      float sum = 0.f;
#pragma unroll
      for (int e = 0; e < 8; ++e) {
        l[e] = expf(l[e] - m);
        sum += l[e];
      }
      float inv = 1.f / sum;
#pragma unroll
      for (int e = 0; e < 8; ++e) {
        float gv = l[e] * inv;
        gws[(size_t)row * 8 + e] = gv;
        g1[(size_t)row * 8 + e] = gv;
        g2[(size_t)row * 8 + e] = gv;
      }
    }
  }
}

extern "C" void kernel_launch(void* const* d_in, const int* in_sizes, int n_in,
                              void* d_out, int out_size, void* d_ws,
                              size_t ws_size, hipStream_t stream) {
  (void)in_sizes; (void)n_in; (void)out_size; (void)ws_size;
  const float* x   = (const float*)d_in[0];
  const float* gW1 = (const float*)d_in[1];
  const float* gb1 = (const float*)d_in[2];
  const float* gW2 = (const float*)d_in[3];
  const float* gb2 = (const float*)d_in[4];
  const float* eW1 = (const float*)d_in[5];
  const float* eb1 = (const float*)d_in[6];
  const float* eW2 = (const float*)d_in[7];
  const float* eb2 = (const float*)d_in[8];

  float* outC  = (float*)d_out;                       // [8192,1024]
  float* outG1 = outC + (size_t)BB * DOUT;            // [8192,8]
  float* outG2 = outG1 + (size_t)BB * NEXP;           // [8192,8]

  char* ws = (char*)d_ws;
  unsigned short* xb   = (unsigned short*)(ws);                 // 16,777,216 B
  unsigned short* gW1T = (unsigned short*)(ws + 16777216);      //  4,194,304 B
  unsigned short* gh   = (unsigned short*)(ws + 20971520);      // 33,554,432 B
  float*          gat  = (float*)(ws + 54525952);               //    262,144 B
  unsigned short* w1T  = (unsigned short*)(ws + 54788096);      //  8,388,608 B
  unsigned short* w2T  = (unsigned short*)(ws + 63176704);      //  8,388,608 B
  unsigned short* hbuf = (unsigned short*)(ws + 71565312);      // 67,108,864 B

  // x -> bf16
  cvt_f32_bf16<<<(BB * DIN / 4) / 256, 256, 0, stream>>>(x, xb, BB * DIN / 4);
  // gW1 [1024][2048] -> gW1T [2048][1024] bf16
  transpose_cvt<<<dim3(GH_N / 32, DIN / 32), 256, 0, stream>>>(gW1, gW1T, DIN, GH_N);
  // gh = relu(x @ gW1 + gb1)  [8192, 2048] bf16   grid 32*8=256
  gemm8<256, 256, 0><<<dim3((BB / 256) * (GH_N / 256)), 512, 0, stream>>>(
      xb, gW1T, BB, GH_N, DIN, gb1, gh, nullptr, nullptr, 0, 0);
  // gates = softmax(gh @ gW2 + gb2)
  gating_head<<<256, 256, 0, stream>>>(gh, gW2, gb2, gat, outG1, outG2, BB, GH_N);

  for (int e = 0; e < NEXP; ++e) {
    // eW1_e [1024][4096] -> w1T [4096][1024]
    transpose_cvt<<<dim3(DHID / 32, DIN / 32), 256, 0, stream>>>(
        eW1 + (size_t)e * DIN * DHID, w1T, DIN, DHID);
    // eW2_e [4096][1024] -> w2T [1024][4096]
    transpose_cvt<<<dim3(DOUT / 32, DHID / 32), 256, 0, stream>>>(
        eW2 + (size_t)e * DHID * DOUT, w2T, DHID, DOUT);
    // h = relu(x @ eW1_e + eb1_e)  [8192, 4096] bf16   grid 32*16=512
    gemm8<256, 256, 0><<<dim3((BB / 256) * (DHID / 256)), 512, 0, stream>>>(
        xb, w1T, BB, DHID, DIN, eb1 + (size_t)e * DHID, hbuf, nullptr, nullptr, 0, 0);
    // combined (+)= gates[:,e] * (h @ eW2_e + eb2_e)   grid 64*4=256 (full chip)
    gemm8<128, 256, 1><<<dim3((BB / 128) * (DOUT / 256)), 512, 0, stream>>>(
        hbuf, w2T, BB, DOUT, DHID, eb2 + (size_t)e * DOUT, nullptr, outC, gat, e, e > 0);
  }
}